// Round 13
// baseline (399.620 us; speedup 1.0000x reference)
//
#include <hip/hip_runtime.h>

// Involution (B=8, H=W=192, C=64, G=4, K=3, R=4) — round 16.
// R15 post-mortem: ring-5/dist-3 FLAT (70us) — per-wave latency depth
// exhausted (R13, R15 both null). Signature VALU~23/HBM~25/occ~24 stable
// across 7 schedules => stall is not schedulable latency.
// Remaining implicated resource: TA/L2 request amplification in Phase A.
// thread=pixel -> each x-load wave-inst touches 64 distinct 128B lines
// (lane stride 256B): 1024 line-requests/wave vs 128 coalesced = 8x on
// the dominant traffic (~600MB L1<->L2 for 75MB of x). Invisible in
// FETCH (L2/L3 absorb) and VALUBusy (TA-queue stall). R10/R11 attacked
// this but confounded with serialization + occupancy loss.
// R16 unconfounded: 4-LANE-PER-PIXEL GEMV SPLIT. No LDS stage, no
// barrier. Lane q of each 4-lane group loads channel-quarter q (4 f4):
// per inst 64 lanes cover 16 px, 2 lanes/line merge -> 32 requests/inst
// (2x cut). td reduced via __shfl_xor(1/2) (quad-perm DPP, ~free); each
// lane computes ke slice e=9q..9q+8 (FMA total unchanged) and writes 9
// b32s (32 banks x 2 lanes = conflict-free). Phase B = R13 verbatim
// (wave-private halves, no barrier, 4-slot ring, mask-0 fences).
// GATES: VGPR 85-115, WRITE == 73728, conflicts ~0, LDS 18432.
// Predict profiled 69.5 -> 55-63 if request theory right; flat 67-72 =>
// theory dead -> declare structural floor next round.

#define B_   8
#define H_   192
#define W_   192
#define CR_  16
#define TH_  8
#define TW_  16
#define TILES_X (W_/TW_)                    // 12
#define TILES_PER_IMG (TILES_X*(H_/TH_))    // 288
#define NBLK (B_*TILES_PER_IMG)             // 2304

constexpr float BN_EPS = 1e-3f;

__device__ __forceinline__ float4 mask4(float4 k, bool v) {
    k.x = v ? k.x : 0.f;
    k.y = v ? k.y : 0.f;
    k.z = v ? k.z : 0.f;
    k.w = v ? k.w : 0.f;
    return k;
}

__device__ __forceinline__ void fma4(float4& a, const float4 k, const float4 x) {
    a.x = fmaf(k.x, x.x, a.x);
    a.y = fmaf(k.y, x.y, a.y);
    a.z = fmaf(k.z, x.z, a.z);
    a.w = fmaf(k.w, x.w, a.w);
}

// ---- Phase B (R13-proven): 4-slot ring, adjacent col pairs, no barrier --
#define LROWS(S, R)                                                         \
    do {                                                                    \
        int rr_ = (R);                                                      \
        if (!INTERIOR) {                                                    \
            if ((unsigned)rr_ < (unsigned)H_) rv |= (1 << (S));             \
            else                              rv &= ~(1 << (S));            \
            rr_ = rr_ < 0 ? 0 : (rr_ >= H_ ? H_ - 1 : rr_);                 \
        }                                                                   \
        const int rb_ = rr_ * (W_ * 16);                                    \
        rg[S][0] = x4[rb_ + co[0]];                                         \
        rg[S][1] = x4[rb_ + co[1]];                                         \
        rg[S][2] = x4[rb_ + co[2]];                                         \
        rg[S][3] = x4[rb_ + co[3]];                                         \
    } while (0)

#define COMP(I)                                                             \
    do {                                                                    \
        const float4* kqA_ = &s_half[((I) * 8 + 2 * j) * 9];                \
        const float4* kqB_ = kqA_ + 9;                                      \
        float4 aA_ = make_float4(0.f, 0.f, 0.f, 0.f);                       \
        float4 aB_ = make_float4(0.f, 0.f, 0.f, 0.f);                       \
        _Pragma("unroll")                                                   \
        for (int ti_ = 0; ti_ < 3; ++ti_) {                                 \
            const int s_ = ((I) + ti_) & 3;                                 \
            _Pragma("unroll")                                               \
            for (int tj_ = 0; tj_ < 3; ++tj_) {                             \
                float4 kA_ = kqA_[ti_ * 3 + tj_];                           \
                float4 kB_ = kqB_[ti_ * 3 + tj_];                           \
                if (!INTERIOR) {                                            \
                    kA_ = mask4(kA_, (((rv >> s_) & (cm >> tj_)) & 1));     \
                    kB_ = mask4(kB_, (((rv >> s_) & (cm >> (tj_ + 1))) & 1));\
                }                                                           \
                fma4(aA_, kA_, rg[s_][tj_]);                                \
                fma4(aB_, kB_, rg[s_][tj_ + 1]);                            \
            }                                                               \
        }                                                                   \
        const int ob_ = (th0 + (I)) * (W_ * 16);                            \
        o4[ob_ + (wA << 4) + c4i] = aA_;                                    \
        o4[ob_ + (wA << 4) + 16 + c4i] = aB_;                               \
    } while (0)

#define SFENCE __builtin_amdgcn_sched_barrier(0)

template <bool INTERIOR>
__device__ __forceinline__ void phase_b(const float4* __restrict__ x4,
                                        float4* __restrict__ o4,
                                        const float4* __restrict__ s_half,
                                        int th0, int tw0w, int ln)
{
    const int j   = ln >> 4;      // col pair 0..3 -> cols 2j, 2j+1
    const int c4i = ln & 15;      // float4 channel chunk
    const int wA  = tw0w + 2 * j;

    int co[4];
    int cm = 0xF;
    #pragma unroll
    for (int tj = 0; tj < 4; ++tj) {
        int wc = wA - 1 + tj;
        if (!INTERIOR) {
            if ((unsigned)wc >= (unsigned)W_) cm &= ~(1 << tj);
            wc = wc < 0 ? 0 : (wc >= W_ ? W_ - 1 : wc);
        }
        co[tj] = (wc << 4) + c4i;
    }

    float4 rg[4][4];   // 64 VGPR ring, all indices static
    int rv = 0xF;

    // Prologue: COMP(0)'s kq ds_reads wait on this wave's own A-writes
    // (in flight) and these 16 loads — no barrier drain, no lockstep.
    LROWS(0, th0 - 1);
    LROWS(1, th0 + 0);
    LROWS(2, th0 + 1);
    LROWS(3, th0 + 2);

    SFENCE;
    COMP(0); LROWS(0, th0 + 3);
    SFENCE;
    COMP(1); LROWS(1, th0 + 4);
    SFENCE;
    COMP(2); LROWS(2, th0 + 5);
    SFENCE;
    COMP(3); LROWS(3, th0 + 6);
    SFENCE;
    COMP(4); LROWS(0, th0 + 7);
    SFENCE;
    COMP(5); LROWS(1, th0 + 8);
    SFENCE;
    COMP(6);
    COMP(7);
}

#undef LROWS
#undef COMP

__global__ __launch_bounds__(128, 2)
void invol_fused(const float* __restrict__ x,
                 const float* __restrict__ w1,
                 const float* __restrict__ b1,
                 const float* __restrict__ gamma,
                 const float* __restrict__ beta,
                 const float* __restrict__ mean,
                 const float* __restrict__ var,
                 const float* __restrict__ w2,
                 const float* __restrict__ b2,
                 float* __restrict__ out)
{
    // Two wave-private halves: 64 px * 9 float4 each = 18 KB total.
    __shared__ float4 s_kern[2][64 * 9];

    const int bid = blockIdx.x;
    // XCD swizzle: 2304 = 8 * 288; each XCD owns one image for L2 locality.
    const int img = bid & 7;
    const int tin = bid >> 3;
    const int th0 = (tin / TILES_X) * TH_;
    const int tw0 = (tin % TILES_X) * TW_;
    const int tid = threadIdx.x;
    const int wv  = tid >> 6;            // wave 0/1
    const int ln  = tid & 63;            // lane
    const int tw0w = tw0 + 8 * wv;       // this wave's 8 columns

    const float4* x4 = reinterpret_cast<const float4*>(x) +
                       (size_t)img * (H_ * W_ * 16);
    float4* o4 = reinterpret_cast<float4*>(out) +
                 (size_t)img * (H_ * W_ * 16);

    // ---------------- Phase A: 4-lane-per-pixel GEMV ------------------------
    // Lane (pslot, q): pixel px = t*16 + pslot per pass t; lane q loads
    // channel-quarter q (4 float4). Per wave-inst: 16 px x 4 q, 2 lanes
    // merging per 128B line -> 32 line-requests (vs 64 for thread=pixel).
    {
        const int q     = ln & 3;        // channel quarter
        const int pslot = ln >> 2;       // pixel within pass 0..15

        // BN coefficients hoisted (identical across passes/lanes).
        float abn[CR_], cbn[CR_];
        #pragma unroll
        for (int d = 0; d < CR_; ++d) {
            abn[d] = gamma[d] * rsqrtf(var[d] + BN_EPS);
            cbn[d] = (b1[d] - mean[d]) * abn[d] + beta[d];
        }

        float* skf = reinterpret_cast<float*>(&s_kern[wv][0]);

        #pragma unroll
        for (int t = 0; t < 4; ++t) {
            const int px = t * 16 + pslot;          // wave-local pixel 0..63
            const int h  = th0 + (px >> 3);
            const int w  = tw0w + (px & 7);
            const float4* xp = reinterpret_cast<const float4*>(
                x + (((size_t)((img * H_ + h) * W_ + w)) << 6)) + q * 4;

            const float4 xv[4] = {xp[0], xp[1], xp[2], xp[3]};

            // partial td from this lane's 16 channels
            float tdp[CR_];
            #pragma unroll
            for (int d = 0; d < CR_; ++d) tdp[d] = 0.f;
            #pragma unroll
            for (int i = 0; i < 4; ++i) {
                const float xs[4] = {xv[i].x, xv[i].y, xv[i].z, xv[i].w};
                #pragma unroll
                for (int k = 0; k < 4; ++k) {
                    const float* wr = w1 + ((q * 4 + i) * 4 + k) * CR_;
                    #pragma unroll
                    for (int d = 0; d < CR_; ++d)
                        tdp[d] = fmaf(xs[k], wr[d], tdp[d]);
                }
            }

            // 4-lane allreduce (xor 1, xor 2 -> quad-perm DPP)
            #pragma unroll
            for (int d = 0; d < CR_; ++d) tdp[d] += __shfl_xor(tdp[d], 1);
            #pragma unroll
            for (int d = 0; d < CR_; ++d) tdp[d] += __shfl_xor(tdp[d], 2);

            // BN + ReLU
            #pragma unroll
            for (int d = 0; d < CR_; ++d)
                tdp[d] = fmaxf(fmaf(tdp[d], abn[d], cbn[d]), 0.f);

            // ke slice e = 9q .. 9q+8 (FMA total per pixel unchanged)
            float ke[9];
            #pragma unroll
            for (int e = 0; e < 9; ++e) ke[e] = b2[9 * q + e];
            #pragma unroll
            for (int d = 0; d < CR_; ++d) {
                const float tv = tdp[d];
                const float* wr = w2 + d * 36 + 9 * q;
                #pragma unroll
                for (int e = 0; e < 9; ++e)
                    ke[e] = fmaf(tv, wr[e], ke[e]);
            }

            // s_kern write: word px*36 + 9q + e. Banks: (4*pslot + 9q + e)
            // mod 32 -> 32 banks x 2 lanes = conflict-free.
            float* sk = skf + px * 36 + 9 * q;
            #pragma unroll
            for (int e = 0; e < 9; ++e) sk[e] = ke[e];
        }
    }

    // NO __syncthreads: all of this wave's 64 px were written by THIS
    // wave's lanes; same-wave ds_write -> ds_read is program-ordered.

    // ---------------- Phase B: 9-tap multiply-reduce (R13 verbatim) ---------
    const bool interior = (th0 > 0) && (th0 + TH_ < H_) &&
                          (tw0 > 0) && (tw0 + TW_ < W_);
    if (interior)
        phase_b<true >(x4, o4, &s_kern[wv][0], th0, tw0w, ln);
    else
        phase_b<false>(x4, o4, &s_kern[wv][0], th0, tw0w, ln);
}

extern "C" void kernel_launch(void* const* d_in, const int* in_sizes, int n_in,
                              void* d_out, int out_size, void* d_ws, size_t ws_size,
                              hipStream_t stream) {
    const float* x     = (const float*)d_in[0];
    const float* w1    = (const float*)d_in[1];
    const float* b1    = (const float*)d_in[2];
    const float* gamma = (const float*)d_in[3];
    const float* beta  = (const float*)d_in[4];
    const float* mean  = (const float*)d_in[5];
    const float* var   = (const float*)d_in[6];
    const float* w2    = (const float*)d_in[7];
    const float* b2    = (const float*)d_in[8];
    float* out = (float*)d_out;

    invol_fused<<<dim3(NBLK), dim3(128), 0, stream>>>(
        x, w1, b1, gamma, beta, mean, var, w2, b2, out);
}